// Round 1
// baseline (701.914 us; speedup 1.0000x reference)
//
#include <hip/hip_runtime.h>
#include <cstddef>

#define CH_HW 4096   // H*W = 64*64

// ---------------------------------------------------------------------------
// Kernel 1: offset field = conv3x3(x, offset_w) + offset_b
// x: (4,256,64,64)  offset_w: (144,256,3,3)  -> offset: (4,144,64,64) in d_ws
// Thread = one pixel, 4 output channels (ocq, ocq+36, ocq+72, ocq+108).
// ---------------------------------------------------------------------------
__global__ __launch_bounds__(256) void offs_conv(const float* __restrict__ x,
                                                 const float* __restrict__ ow,
                                                 const float* __restrict__ ob,
                                                 float* __restrict__ offset)
{
    const int rt  = blockIdx.x;   // 0..15 row tiles (4 rows each)
    const int ocq = blockIdx.y;   // 0..35
    const int b   = blockIdx.z;   // 0..3
    const int tid = threadIdx.x;
    const int w = tid & 63;
    const int h = (rt << 2) + (tid >> 6);

    // hoisted tap addresses (clamped -> always safe) + zero masks
    int offs[9]; float msk[9];
#pragma unroll
    for (int t = 0; t < 9; ++t) {
        const int dy = t / 3 - 1, dx = t % 3 - 1;
        const int hh = h + dy, ww = w + dx;
        const int hc = min(max(hh, 0), 63);
        const int wc = min(max(ww, 0), 63);
        offs[t] = (hc << 6) + wc;
        msk[t] = (hh >= 0 && hh < 64 && ww >= 0 && ww < 64) ? 1.0f : 0.0f;
    }

    float acc0 = 0.f, acc1 = 0.f, acc2 = 0.f, acc3 = 0.f;
    const float* xp  = x + (size_t)b * 256 * CH_HW;
    const float* wp0 = ow + (size_t)(ocq)*2304;
    const float* wp1 = ow + (size_t)(ocq + 36) * 2304;
    const float* wp2 = ow + (size_t)(ocq + 72) * 2304;
    const float* wp3 = ow + (size_t)(ocq + 108) * 2304;

    for (int ic = 0; ic < 256; ++ic) {
        float xv[9];
#pragma unroll
        for (int t = 0; t < 9; ++t) xv[t] = xp[offs[t]] * msk[t];
#pragma unroll
        for (int t = 0; t < 9; ++t) {
            acc0 = fmaf(xv[t], wp0[t], acc0);
            acc1 = fmaf(xv[t], wp1[t], acc1);
            acc2 = fmaf(xv[t], wp2[t], acc2);
            acc3 = fmaf(xv[t], wp3[t], acc3);
        }
        xp += CH_HW; wp0 += 9; wp1 += 9; wp2 += 9; wp3 += 9;
    }

    const int pix = (h << 6) + w;
    float* op = offset + (size_t)b * 144 * CH_HW + pix;
    op[(size_t)(ocq)*CH_HW]       = acc0 + ob[ocq];
    op[(size_t)(ocq + 36) * CH_HW]  = acc1 + ob[ocq + 36];
    op[(size_t)(ocq + 72) * CH_HW]  = acc2 + ob[ocq + 72];
    op[(size_t)(ocq + 108) * CH_HW] = acc3 + ob[ocq + 108];
}

// ---------------------------------------------------------------------------
// Kernel 2: bilinear deformable sampling + grouped conv + bias
// ---------------------------------------------------------------------------
struct Samp { int iA, iB, iC, iD; float wA, wB, wC, wD; };

__device__ inline Samp make_samp(float py, float px) {
    const float y0f = floorf(py), x0f = floorf(px);
    const int iy0 = (int)y0f, ix0 = (int)x0f;
    const int iy1 = iy0 + 1,  ix1 = ix0 + 1;
    const float fy1 = py - y0f, fx1 = px - x0f;
    const float fy0 = 1.f - fy1, fx0 = 1.f - fx1;
    const bool vy0 = (iy0 >= 0) & (iy0 < 64);
    const bool vy1 = (iy1 >= 0) & (iy1 < 64);
    const bool vx0 = (ix0 >= 0) & (ix0 < 64);
    const bool vx1 = (ix1 >= 0) & (ix1 < 64);
    const int cy0 = min(max(iy0, 0), 63), cy1 = min(max(iy1, 0), 63);
    const int cx0 = min(max(ix0, 0), 63), cx1 = min(max(ix1, 0), 63);
    Samp s;
    s.iA = (cy0 << 6) + cx0; s.iB = (cy0 << 6) + cx1;
    s.iC = (cy1 << 6) + cx0; s.iD = (cy1 << 6) + cx1;
    s.wA = (vy0 & vx0) ? fy0 * fx0 : 0.f;
    s.wB = (vy0 & vx1) ? fy0 * fx1 : 0.f;
    s.wC = (vy1 & vx0) ? fy1 * fx0 : 0.f;
    s.wD = (vy1 & vx1) ? fy1 * fx1 : 0.f;
    return s;
}

__global__ __launch_bounds__(256) void deform_apply(const float* __restrict__ x,
                                                    const float* __restrict__ offset,
                                                    const float* __restrict__ dw,
                                                    const float* __restrict__ db,
                                                    float* __restrict__ out)
{
    __shared__ float wlds[9216];   // [c*9+k][o], o contiguous for float4 reads
    const int chunk = blockIdx.x;  // 0..7  (512 pixels each)
    const int g = blockIdx.y;      // 0..7
    const int b = blockIdx.z;      // 0..3
    const int tid = threadIdx.x;

    // stage group weights: dw[(g*32+o)][c][3][3] -> wlds[(c*9+k)*32 + o]
    for (int d = tid; d < 9216; d += 256) {
        const int o = d & 31, ck = d >> 5;
        wlds[d] = dw[(size_t)(g * 32 + o) * 288 + ck];
    }
    __syncthreads();

    const int pix0 = (chunk << 9) + tid;
    const int pix1 = pix0 + 256;
    const int h0 = pix0 >> 6, w0c = pix0 & 63;
    const int h1 = pix1 >> 6, w1c = pix1 & 63;

    const float* xg   = x + ((size_t)b * 256 + g * 32) * CH_HW;
    const float* offp = offset + ((size_t)b * 144 + g * 18) * CH_HW;

    float acc0[32], acc1[32];
#pragma unroll
    for (int o = 0; o < 32; ++o) { acc0[o] = 0.f; acc1[o] = 0.f; }

    for (int k = 0; k < 9; ++k) {
        const int ki = k / 3, kj = k % 3;
        const float oy0 = offp[(size_t)(2 * k) * CH_HW + pix0];
        const float ox0 = offp[(size_t)(2 * k + 1) * CH_HW + pix0];
        const float oy1 = offp[(size_t)(2 * k) * CH_HW + pix1];
        const float ox1 = offp[(size_t)(2 * k + 1) * CH_HW + pix1];
        const Samp s0 = make_samp((float)(h0 - 1 + ki) + oy0,
                                  (float)(w0c - 1 + kj) + ox0);
        const Samp s1 = make_samp((float)(h1 - 1 + ki) + oy1,
                                  (float)(w1c - 1 + kj) + ox1);

        for (int c = 0; c < 32; ++c) {
            const float* xc = xg + (size_t)c * CH_HW;
            const float v0 = s0.wA * xc[s0.iA] + s0.wB * xc[s0.iB] +
                             s0.wC * xc[s0.iC] + s0.wD * xc[s0.iD];
            const float v1 = s1.wA * xc[s1.iA] + s1.wB * xc[s1.iB] +
                             s1.wC * xc[s1.iC] + s1.wD * xc[s1.iD];
            const float4* wr = (const float4*)&wlds[(c * 9 + k) << 5];
#pragma unroll
            for (int o4 = 0; o4 < 8; ++o4) {
                const float4 wv = wr[o4];
                acc0[o4 * 4 + 0] = fmaf(v0, wv.x, acc0[o4 * 4 + 0]);
                acc0[o4 * 4 + 1] = fmaf(v0, wv.y, acc0[o4 * 4 + 1]);
                acc0[o4 * 4 + 2] = fmaf(v0, wv.z, acc0[o4 * 4 + 2]);
                acc0[o4 * 4 + 3] = fmaf(v0, wv.w, acc0[o4 * 4 + 3]);
                acc1[o4 * 4 + 0] = fmaf(v1, wv.x, acc1[o4 * 4 + 0]);
                acc1[o4 * 4 + 1] = fmaf(v1, wv.y, acc1[o4 * 4 + 1]);
                acc1[o4 * 4 + 2] = fmaf(v1, wv.z, acc1[o4 * 4 + 2]);
                acc1[o4 * 4 + 3] = fmaf(v1, wv.w, acc1[o4 * 4 + 3]);
            }
        }
    }

#pragma unroll
    for (int o = 0; o < 32; ++o) {
        const float bias = db[g * 32 + o];
        float* op = out + ((size_t)b * 256 + g * 32 + o) * CH_HW;
        op[pix0] = acc0[o] + bias;
        op[pix1] = acc1[o] + bias;
    }
}

// ---------------------------------------------------------------------------
extern "C" void kernel_launch(void* const* d_in, const int* in_sizes, int n_in,
                              void* d_out, int out_size, void* d_ws, size_t ws_size,
                              hipStream_t stream) {
    const float* x  = (const float*)d_in[0];
    const float* ow = (const float*)d_in[1];
    const float* ob = (const float*)d_in[2];
    const float* dw = (const float*)d_in[3];
    const float* db = (const float*)d_in[4];
    float* out = (float*)d_out;
    float* off = (float*)d_ws;   // 4*144*64*64*4 = 9.44 MB scratch

    offs_conv<<<dim3(16, 36, 4), 256, 0, stream>>>(x, ow, ob, off);
    deform_apply<<<dim3(8, 8, 4), 256, 0, stream>>>(x, off, dw, db, out);
}

// Round 2
// 173.320 us; speedup vs baseline: 4.0498x; 4.0498x over previous
//
#include <hip/hip_runtime.h>
#include <hip/hip_bf16.h>
#include <cstddef>
#include <cstdint>

#define CH_HW 4096   // 64*64

typedef __bf16  bf16x8  __attribute__((ext_vector_type(8)));
typedef float   f32x4   __attribute__((ext_vector_type(4)));
typedef unsigned int u32x4 __attribute__((ext_vector_type(4)));

// d_ws layout: [0, WF_BYTES) packed bf16 weights; then bf16 offset field
#define WF_ELEMS 331776            // 72 ks * 9 nt * 64 lane * 8
#define WF_BYTES (WF_ELEMS * 2)    // 663,552
// offsets: 4*144*4096 bf16 = 4,718,592 B ; total 5.38 MB (< 9.44 MB proven)

// ---------------------------------------------------------------------------
// Kernel 0: repack offset_w (144,256,3,3) f32 -> MFMA B-fragment stream bf16
// Wf[ks][nt][lane][j]; ks = tap*8+icb; oc = nt*16+(lane&15);
// ic = icb*32+(lane>>4)*8+j
// ---------------------------------------------------------------------------
__global__ __launch_bounds__(256) void repack_w(const float* __restrict__ ow,
                                                __hip_bfloat16* __restrict__ wf)
{
    const int t = blockIdx.x * 256 + threadIdx.x;
    if (t >= WF_ELEMS) return;
    const int j    = t & 7;
    const int lane = (t >> 3) & 63;
    const int tmp  = t >> 9;         // ks*9 + nt
    const int nt   = tmp % 9;
    const int ks   = tmp / 9;
    const int tap  = ks >> 3, icb = ks & 7;
    const int oc   = nt * 16 + (lane & 15);
    const int ic   = icb * 32 + (lane >> 4) * 8 + j;
    wf[t] = __float2bfloat16(ow[(size_t)oc * 2304 + ic * 9 + tap]);
}

// ---------------------------------------------------------------------------
// Kernel 1: offset conv as implicit-GEMM MFMA (bf16 in, fp32 acc, bf16 out)
// block = one (b, hrow): 64 pixels x 144 oc. 4 waves, wave w = rows w*16..+16.
// ---------------------------------------------------------------------------
__device__ __forceinline__ void stageA_load(const float* __restrict__ xb,
                                            int hrow, int m, int kc, int ks,
                                            float av[8])
{
    const int tap = ks >> 3, icb = ks & 7;
    const int dy = tap / 3 - 1, dx = tap % 3 - 1;
    const int sh = hrow + dy, sw = m + dx;
    const float msk = (sh >= 0 && sh < 64 && sw >= 0 && sw < 64) ? 1.f : 0.f;
    const int shc = min(max(sh, 0), 63), swc = min(max(sw, 0), 63);
    const float* p = xb + (size_t)(icb * 32 + kc * 8) * CH_HW + (shc << 6) + swc;
#pragma unroll
    for (int j = 0; j < 8; ++j) av[j] = p[(size_t)j * CH_HW] * msk;
}

__global__ __launch_bounds__(256) void offs_mfma(const float* __restrict__ x,
                                                 const __hip_bfloat16* __restrict__ wf,
                                                 const float* __restrict__ ob,
                                                 __hip_bfloat16* __restrict__ offw)
{
    __shared__ __align__(16) unsigned short aL[2][64][40];  // padded 80B rows
    __shared__ __align__(16) unsigned short bL[2][4608];    // [ (nt*64+lane)*8 ]

    const int bid  = blockIdx.x;
    const int b    = bid >> 6, hrow = bid & 63;
    const int tid  = threadIdx.x;
    const int lane = tid & 63, wave = tid >> 6;
    const int m    = lane;   // staging pixel col
    const int kc   = wave;   // staging k-chunk (8 ic each)

    const float* xb = x + (size_t)b * 256 * CH_HW;

    f32x4 acc[9];
#pragma unroll
    for (int nt = 0; nt < 9; ++nt) acc[nt] = (f32x4){0.f, 0.f, 0.f, 0.f};

    // ---- prologue: stage ks=0 into buf 0
    {
        float av[8]; u32x4 bv[3];
        stageA_load(xb, hrow, m, kc, 0, av);
#pragma unroll
        for (int q = 0; q < 3; ++q) {
            const int nt = wave + q * 4;
            if (nt < 9) bv[q] = *(const u32x4*)(wf + ((size_t)nt * 64 + lane) * 8);
        }
        u32x4 ad;
#pragma unroll
        for (int jj = 0; jj < 4; ++jj) {
            const unsigned int lo = __builtin_bit_cast(unsigned short, __float2bfloat16(av[2 * jj]));
            const unsigned int hi = __builtin_bit_cast(unsigned short, __float2bfloat16(av[2 * jj + 1]));
            ad[jj] = lo | (hi << 16);
        }
        *(u32x4*)&aL[0][m][kc * 8] = ad;
#pragma unroll
        for (int q = 0; q < 3; ++q) {
            const int nt = wave + q * 4;
            if (nt < 9) *(u32x4*)&bL[0][nt * 512 + lane * 8] = bv[q];
        }
    }
    __syncthreads();

    // ---- main loop
    for (int ks = 0; ks < 72; ++ks) {
        const int buf = ks & 1, nbuf = buf ^ 1;
        const bool hasNext = (ks + 1) < 72;

        float av[8]; u32x4 bv[3];
        if (hasNext) {
            stageA_load(xb, hrow, m, kc, ks + 1, av);
#pragma unroll
            for (int q = 0; q < 3; ++q) {
                const int nt = wave + q * 4;
                if (nt < 9)
                    bv[q] = *(const u32x4*)(wf + ((size_t)((ks + 1) * 9 + nt) * 64 + lane) * 8);
            }
        }

        // compute current
        const u32x4 au = *(const u32x4*)&aL[buf][wave * 16 + (lane & 15)][(lane >> 4) * 8];
        const bf16x8 afr = __builtin_bit_cast(bf16x8, au);
#pragma unroll
        for (int nt = 0; nt < 9; ++nt) {
            const u32x4 bu = *(const u32x4*)&bL[buf][nt * 512 + lane * 8];
            acc[nt] = __builtin_amdgcn_mfma_f32_16x16x32_bf16(
                afr, __builtin_bit_cast(bf16x8, bu), acc[nt], 0, 0, 0);
        }

        if (hasNext) {
            u32x4 ad;
#pragma unroll
            for (int jj = 0; jj < 4; ++jj) {
                const unsigned int lo = __builtin_bit_cast(unsigned short, __float2bfloat16(av[2 * jj]));
                const unsigned int hi = __builtin_bit_cast(unsigned short, __float2bfloat16(av[2 * jj + 1]));
                ad[jj] = lo | (hi << 16);
            }
            *(u32x4*)&aL[nbuf][m][kc * 8] = ad;
#pragma unroll
            for (int q = 0; q < 3; ++q) {
                const int nt = wave + q * 4;
                if (nt < 9) *(u32x4*)&bL[nbuf][nt * 512 + lane * 8] = bv[q];
            }
        }
        __syncthreads();
    }

    // ---- epilogue: C[m][oc], col(oc)=lane&15, row(m)=(lane>>4)*4+r
    const int oc_l = lane & 15;
    const int mrow = wave * 16 + ((lane >> 4) << 2);
#pragma unroll
    for (int nt = 0; nt < 9; ++nt) {
        const int oc = nt * 16 + oc_l;
        const float bias = ob[oc];
        __hip_bfloat16* op = offw + ((size_t)b * 144 + oc) * CH_HW + hrow * 64 + mrow;
#pragma unroll
        for (int r = 0; r < 4; ++r)
            op[r] = __float2bfloat16(acc[nt][r] + bias);
    }
}

// ---------------------------------------------------------------------------
// Kernel 2: bilinear deformable sampling + grouped conv + bias
// 1 pixel/thread; 9 Samps precomputed; c-outer k-inner for L1 reuse.
// ---------------------------------------------------------------------------
struct Samp { int iA, iB, iC, iD; float wA, wB, wC, wD; };

__device__ __forceinline__ Samp make_samp(float py, float px) {
    const float y0f = floorf(py), x0f = floorf(px);
    const int iy0 = (int)y0f, ix0 = (int)x0f;
    const int iy1 = iy0 + 1,  ix1 = ix0 + 1;
    const float fy1 = py - y0f, fx1 = px - x0f;
    const float fy0 = 1.f - fy1, fx0 = 1.f - fx1;
    const bool vy0 = (iy0 >= 0) & (iy0 < 64);
    const bool vy1 = (iy1 >= 0) & (iy1 < 64);
    const bool vx0 = (ix0 >= 0) & (ix0 < 64);
    const bool vx1 = (ix1 >= 0) & (ix1 < 64);
    const int cy0 = min(max(iy0, 0), 63), cy1 = min(max(iy1, 0), 63);
    const int cx0 = min(max(ix0, 0), 63), cx1 = min(max(ix1, 0), 63);
    Samp s;
    s.iA = (cy0 << 6) + cx0; s.iB = (cy0 << 6) + cx1;
    s.iC = (cy1 << 6) + cx0; s.iD = (cy1 << 6) + cx1;
    s.wA = (vy0 & vx0) ? fy0 * fx0 : 0.f;
    s.wB = (vy0 & vx1) ? fy0 * fx1 : 0.f;
    s.wC = (vy1 & vx0) ? fy1 * fx0 : 0.f;
    s.wD = (vy1 & vx1) ? fy1 * fx1 : 0.f;
    return s;
}

__global__ __launch_bounds__(256) void deform2(const float* __restrict__ x,
                                               const __hip_bfloat16* __restrict__ offw,
                                               const float* __restrict__ dw,
                                               const float* __restrict__ db,
                                               float* __restrict__ out)
{
    __shared__ float wlds[9216];   // [c*9+k][o]
    const int chunk = blockIdx.x;  // 0..15 (256 pixels each)
    const int g = blockIdx.y;
    const int b = blockIdx.z;
    const int tid = threadIdx.x;

    for (int d = tid; d < 9216; d += 256) {
        const int o = d & 31, ck = d >> 5;
        wlds[d] = dw[(size_t)(g * 32 + o) * 288 + ck];
    }
    __syncthreads();

    const int pix = (chunk << 8) + tid;
    const int h = pix >> 6, w = pix & 63;

    const __hip_bfloat16* offp = offw + ((size_t)b * 144 + g * 18) * CH_HW + pix;
    Samp sp[9];
#pragma unroll
    for (int k = 0; k < 9; ++k) {
        const float oy = __bfloat162float(offp[(size_t)(2 * k) * CH_HW]);
        const float ox = __bfloat162float(offp[(size_t)(2 * k + 1) * CH_HW]);
        sp[k] = make_samp((float)(h - 1 + k / 3) + oy, (float)(w - 1 + k % 3) + ox);
    }

    const float* xg = x + ((size_t)b * 256 + g * 32) * CH_HW;
    float acc[32];
#pragma unroll
    for (int o = 0; o < 32; ++o) acc[o] = 0.f;

    for (int c = 0; c < 32; ++c) {
        const float* xc = xg + (size_t)c * CH_HW;
#pragma unroll
        for (int k = 0; k < 9; ++k) {
            const Samp s = sp[k];
            const float v = s.wA * xc[s.iA] + s.wB * xc[s.iB] +
                            s.wC * xc[s.iC] + s.wD * xc[s.iD];
            const float4* wr = (const float4*)&wlds[(c * 9 + k) << 5];
#pragma unroll
            for (int o4 = 0; o4 < 8; ++o4) {
                const float4 wv = wr[o4];
                acc[o4 * 4 + 0] = fmaf(v, wv.x, acc[o4 * 4 + 0]);
                acc[o4 * 4 + 1] = fmaf(v, wv.y, acc[o4 * 4 + 1]);
                acc[o4 * 4 + 2] = fmaf(v, wv.z, acc[o4 * 4 + 2]);
                acc[o4 * 4 + 3] = fmaf(v, wv.w, acc[o4 * 4 + 3]);
            }
        }
    }

#pragma unroll
    for (int o = 0; o < 32; ++o) {
        float* op = out + ((size_t)b * 256 + g * 32 + o) * CH_HW;
        op[pix] = acc[o] + db[g * 32 + o];
    }
}

// ---------------------------------------------------------------------------
extern "C" void kernel_launch(void* const* d_in, const int* in_sizes, int n_in,
                              void* d_out, int out_size, void* d_ws, size_t ws_size,
                              hipStream_t stream) {
    const float* x  = (const float*)d_in[0];
    const float* ow = (const float*)d_in[1];
    const float* ob = (const float*)d_in[2];
    const float* dw = (const float*)d_in[3];
    const float* db = (const float*)d_in[4];
    float* out = (float*)d_out;

    __hip_bfloat16* wf   = (__hip_bfloat16*)d_ws;
    __hip_bfloat16* offw = (__hip_bfloat16*)((char*)d_ws + WF_BYTES);

    repack_w<<<(WF_ELEMS + 255) / 256, 256, 0, stream>>>(ow, wf);
    offs_mfma<<<256, 256, 0, stream>>>(x, wf, ob, offw);
    deform2<<<dim3(16, 8, 4), 256, 0, stream>>>(x, offw, dw, db, out);
}